// Round 6
// baseline (546.899 us; speedup 1.0000x reference)
//
#include <hip/hip_runtime.h>
#include <cstdint>
#include <cstddef>

#define NLVL 4
#define TSIZE (1u << 19)
#define NH 64
#define NOUT 128
#define MBLK 64            // points per workgroup (2 waves)

typedef _Float16 f16x8 __attribute__((ext_vector_type(8)));
typedef _Float16 f16x2 __attribute__((ext_vector_type(2)));
typedef float f32x4 __attribute__((ext_vector_type(4)));
typedef unsigned short u16x8 __attribute__((ext_vector_type(8)));

__device__ __forceinline__ float fsin_rad(float x) {
    return __builtin_amdgcn_sinf(__builtin_amdgcn_fractf(x * 0.15915494309189535f));
}
__device__ __forceinline__ float fsin_rev(float r) {
    return __builtin_amdgcn_sinf(__builtin_amdgcn_fractf(r));
}
__device__ __forceinline__ unsigned short h2u(_Float16 h) {
    return __builtin_bit_cast(unsigned short, h);
}

// ---- prep kernel 1: transpose weights to [col][k] layout, f16, into d_ws ----
// ws layout (f16 elems): WsT 0..16384, WoutT 16384..49152, ffnT 49152..51200
__global__ void prep_weights(const float* __restrict__ Ws,
                             const float* __restrict__ Wout,
                             const float* __restrict__ ffn,
                             _Float16* __restrict__ ws)
{
    int i = blockIdx.x * 256 + threadIdx.x;
    _Float16* WsT = ws;            // [4][64 col][64 k]
    _Float16* WoT = ws + 16384;    // [4][128 col][64 k]
    _Float16* FfT = ws + 49152;    // [4][64 col][8 k]
    if (i < 16384) {
        int l = i >> 12, r = i & 4095, k = r >> 6, c = r & 63;
        WsT[l * 4096 + c * 64 + k] = (_Float16)Ws[i];
    } else if (i < 49152) {
        int j = i - 16384;
        int l = j >> 13, r = j & 8191, k = r >> 7, c = r & 127;
        WoT[l * 8192 + c * 64 + k] = (_Float16)Wout[j];
    } else if (i < 51200) {
        int j = i - 49152;
        int l = j >> 9, r = j & 511, k = r >> 6, c = r & 63;
        FfT[l * 512 + c * 8 + k] = (_Float16)ffn[j];
    }
}

// ---- prep kernel 2: table f32 -> f16 * 4096 (halves gather bytes; fits L2/L3) ----
__global__ __launch_bounds__(256) void prep_table(const float* __restrict__ table,
                                                  _Float16* __restrict__ tab16)
{
    int i = blockIdx.x * 256 + threadIdx.x;            // 16,777,216 elems
    float v = __builtin_nontemporal_load(table + i);   // stream, don't pollute L3
    tab16[i] = (_Float16)(v * 4096.f);
}

template <bool F16TAB>
__global__ __launch_bounds__(128, 6)
void ffb_main(const float* __restrict__ in_pos,
              const float* __restrict__ table,
              const _Float16* __restrict__ tab16,
              const float* __restrict__ W0,
              const float* __restrict__ b0,
              const float* __restrict__ bs,
              const float* __restrict__ bout,
              const _Float16* __restrict__ ws,
              float* __restrict__ out)
{
    // X plane: [64 rows][64 cols] f16, XOR-swizzled: idx = row*64 + (col ^ ((row&7)<<3))
    __shared__ __align__(16) unsigned short Xh[MBLK * NH];
    __shared__ __align__(16) unsigned short gS[NLVL][MBLK][8];   // g scaled by 4096, f16

    const int tid = threadIdx.x;
    const int pbase = blockIdx.x * MBLK;

    // ---------- stage 1: hash-grid gather (2 levels per thread) + layer0 ----------
    {
        const int p = tid & (MBLK - 1);
        const float px = in_pos[3 * (pbase + p) + 0];
        const float py = in_pos[3 * (pbase + p) + 1];
        const float pz = in_pos[3 * (pbase + p) + 2];
        const float qx = (px + 1.f) * 0.5f, qy = (py + 1.f) * 0.5f, qz = (pz + 1.f) * 0.5f;
        const uint32_t P1 = 2654435761u, P2 = 805459861u;
        const int lv0 = (tid >> 6) * 2;

        if (F16TAB) {
            uint32_t hh[2][8];
            float    wgt[2][8];
            #pragma unroll
            for (int t = 0; t < 2; ++t) {
                const int lv = lv0 + t;
                const float res = (float)(16 << lv);
                float gx = qx * res, gy = qy * res, gz = qz * res;
                float fx0 = floorf(gx), fy0 = floorf(gy), fz0 = floorf(gz);
                float fx = gx - fx0, fy = gy - fy0, fz = gz - fz0;
                uint32_t ux = (uint32_t)fx0, uy = (uint32_t)fy0, uz = (uint32_t)fz0;
                uint32_t hx0 = ux, hx1 = ux + 1u;
                uint32_t hy0 = uy * P1, hy1 = hy0 + P1;
                uint32_t hz0 = uz * P2, hz1 = hz0 + P2;
                #pragma unroll
                for (int c = 0; c < 8; ++c) {
                    hh[t][c] = (((c & 4) ? hx1 : hx0) ^ ((c & 2) ? hy1 : hy0)
                                ^ ((c & 1) ? hz1 : hz0)) & (TSIZE - 1u);
                    wgt[t][c] = ((c & 4) ? fx : 1.f - fx) * ((c & 2) ? fy : 1.f - fy)
                              * ((c & 1) ? fz : 1.f - fz);
                }
            }
            // issue all 16 gather loads (16B each), then interpolate in packed f16
            u16x8 vv[2][8];
            #pragma unroll
            for (int t = 0; t < 2; ++t) {
                const _Float16* tl = tab16 + (size_t)(lv0 + t) * TSIZE * 8;
                #pragma unroll
                for (int c = 0; c < 8; ++c)
                    vv[t][c] = *(const u16x8*)(tl + (size_t)hh[t][c] * 8);
            }
            #pragma unroll
            for (int t = 0; t < 2; ++t) {
                f16x2 acc2[4];
                #pragma unroll
                for (int q = 0; q < 4; ++q) acc2[q] = (f16x2){(_Float16)0.f, (_Float16)0.f};
                #pragma unroll
                for (int c = 0; c < 8; ++c) {
                    _Float16 wh = (_Float16)wgt[t][c];
                    f16x2 ww = {wh, wh};
                    const f16x2* vp = (const f16x2*)&vv[t][c];
                    #pragma unroll
                    for (int q = 0; q < 4; ++q) acc2[q] = acc2[q] + ww * vp[q];  // v_pk_fma_f16
                }
                *(u16x8*)&gS[lv0 + t][p][0] = *(u16x8*)&acc2[0];
            }
        } else {
            #pragma unroll 1
            for (int t = 0; t < 2; ++t) {
                const int lv = lv0 + t;
                const float res = (float)(16 << lv);
                float gx = qx * res, gy = qy * res, gz = qz * res;
                float fx0 = floorf(gx), fy0 = floorf(gy), fz0 = floorf(gz);
                float fx = gx - fx0, fy = gy - fy0, fz = gz - fz0;
                uint32_t ux = (uint32_t)fx0, uy = (uint32_t)fy0, uz = (uint32_t)fz0;
                uint32_t hx0 = ux, hx1 = ux + 1u;
                uint32_t hy0 = uy * P1, hy1 = hy0 + P1;
                uint32_t hz0 = uz * P2, hz1 = hz0 + P2;
                const float* tl = table + (size_t)lv * TSIZE * 8;
                float g[8];
                #pragma unroll
                for (int q = 0; q < 8; ++q) g[q] = 0.f;
                #pragma unroll
                for (int c = 0; c < 8; ++c) {
                    uint32_t h = (((c & 4) ? hx1 : hx0) ^ ((c & 2) ? hy1 : hy0)
                                  ^ ((c & 1) ? hz1 : hz0)) & (TSIZE - 1u);
                    float w = ((c & 4) ? fx : 1.f - fx) * ((c & 2) ? fy : 1.f - fy)
                            * ((c & 1) ? fz : 1.f - fz);
                    const float4* fp = (const float4*)(tl + (size_t)h * 8);
                    float4 va = fp[0], vb = fp[1];
                    g[0] = fmaf(w, va.x, g[0]); g[1] = fmaf(w, va.y, g[1]);
                    g[2] = fmaf(w, va.z, g[2]); g[3] = fmaf(w, va.w, g[3]);
                    g[4] = fmaf(w, vb.x, g[4]); g[5] = fmaf(w, vb.y, g[5]);
                    g[6] = fmaf(w, vb.z, g[6]); g[7] = fmaf(w, vb.w, g[7]);
                }
                u16x8 gv;
                #pragma unroll
                for (int q = 0; q < 8; ++q)
                    gv[q] = h2u((_Float16)(g[q] * 4096.f));
                *(u16x8*)&gS[lv][p][0] = gv;
            }
        }
        // layer0: x0 = sin(30*(pos@W0 + b0)); this thread does 32 cols of point p
        const int ch = (tid >> 6) * 32;
        #pragma unroll 4
        for (int c = ch; c < ch + 32; c += 2) {
            float a0 = b0[c]     + px * W0[c]       + py * W0[64 + c]  + pz * W0[128 + c];
            float a1 = b0[c + 1] + px * W0[c + 1]   + py * W0[65 + c]  + pz * W0[129 + c];
            _Float16 h0 = (_Float16)fsin_rad(30.f * a0);
            _Float16 h1 = (_Float16)fsin_rad(30.f * a1);
            int idx = p * 64 + (c ^ ((p & 7) << 3));
            *(unsigned int*)&Xh[idx] = (unsigned int)h2u(h0) | ((unsigned int)h2u(h1) << 16);
        }
    }
    __syncthreads();
    // After this barrier: wave wv exclusively owns X-plane rows [wv*32, wv*32+32). No more barriers.

    const int lane = tid & 63;
    const int wv = tid >> 6;
    const int r15 = lane & 15;
    const int hi4 = lane >> 4;
    const char* Xhb = (const char*)Xh;

    // A-fragments (held across phases): lane -> row = base + (lane&15), k = kb*32 + (lane>>4)*8 + j
    f16x8 Axh[2][2];
    auto loadA = [&]() {
        #pragma unroll
        for (int rt = 0; rt < 2; ++rt)
            #pragma unroll
            for (int kb = 0; kb < 2; ++kb) {
                int row = wv * 32 + rt * 16 + r15;
                int off = row * 128 + ((kb * 64 + hi4 * 16) ^ ((row & 7) << 4));
                Axh[rt][kb] = *(const f16x8*)(Xhb + off);
            }
    };
    loadA();

    float acc[2][8][4];
    #pragma unroll
    for (int rt = 0; rt < 2; ++rt)
        #pragma unroll
        for (int ct = 0; ct < 8; ++ct)
            #pragma unroll
            for (int r = 0; r < 4; ++r) acc[rt][ct][r] = 0.f;

    const _Float16* WsT = ws;
    const _Float16* WoT = ws + 16384;
    const _Float16* FfT = ws + 49152;

    #pragma unroll 1
    for (int lvl = 0; lvl < NLVL; ++lvl) {
        // g A-frags: only lanes 0-15 carry k<8; rest zero
        f16x8 Ag[2];
        #pragma unroll
        for (int rt = 0; rt < 2; ++rt) {
            f16x8 z;
            #pragma unroll
            for (int q = 0; q < 8; ++q) z[q] = (_Float16)0.f;
            if (lane < 16)
                z = *(const f16x8*)&gS[lvl][wv * 32 + rt * 16 + lane][0];
            Ag[rt] = z;
        }

        // ---- phase B: xn = sin(30*(X@Ws + bs)) + sin(2pi*(g@ffn)) ----
        #pragma unroll
        for (int ct = 0; ct < 4; ++ct) {
            const _Float16* bp = WsT + lvl * 4096 + (ct * 16 + r15) * 64 + hi4 * 8;
            f16x8 B0 = *(const f16x8*)bp;          // kb = 0
            f16x8 B1 = *(const f16x8*)(bp + 32);   // kb = 1
            f16x8 Bf;
            #pragma unroll
            for (int q = 0; q < 8; ++q) Bf[q] = (_Float16)0.f;
            if (lane < 16)
                Bf = *(const f16x8*)(FfT + lvl * 512 + (ct * 16 + r15) * 8);
            float bsv = bs[lvl * 64 + ct * 16 + r15];
            #pragma unroll
            for (int rt = 0; rt < 2; ++rt) {
                f32x4 c1 = {0.f, 0.f, 0.f, 0.f};
                c1 = __builtin_amdgcn_mfma_f32_16x16x32_f16(Axh[rt][0], B0, c1, 0, 0, 0);
                c1 = __builtin_amdgcn_mfma_f32_16x16x32_f16(Axh[rt][1], B1, c1, 0, 0, 0);
                f32x4 c2 = {0.f, 0.f, 0.f, 0.f};
                c2 = __builtin_amdgcn_mfma_f32_16x16x32_f16(Ag[rt], Bf, c2, 0, 0, 0);
                #pragma unroll
                for (int r = 0; r < 4; ++r) {
                    int row = wv * 32 + rt * 16 + hi4 * 4 + r;
                    int col = ct * 16 + r15;
                    float xn = fsin_rad(30.f * (c1[r] + bsv))
                             + fsin_rev(c2[r] * 0.000244140625f);  // /4096
                    int idx = row * 64 + (col ^ ((row & 7) << 3));
                    Xh[idx] = h2u((_Float16)xn);
                }
            }
        }
        loadA();   // new x -> A-frags (also reused by next level's phase B)

        // ---- phase C: out += sin(30*(x@Wout + bout)) ----
        #pragma unroll
        for (int ct = 0; ct < 8; ++ct) {
            const _Float16* bp = WoT + lvl * 8192 + (ct * 16 + r15) * 64 + hi4 * 8;
            f16x8 B0 = *(const f16x8*)bp;
            f16x8 B1 = *(const f16x8*)(bp + 32);
            float bov = bout[lvl * 128 + ct * 16 + r15];
            #pragma unroll
            for (int rt = 0; rt < 2; ++rt) {
                f32x4 c = {0.f, 0.f, 0.f, 0.f};
                c = __builtin_amdgcn_mfma_f32_16x16x32_f16(Axh[rt][0], B0, c, 0, 0, 0);
                c = __builtin_amdgcn_mfma_f32_16x16x32_f16(Axh[rt][1], B1, c, 0, 0, 0);
                #pragma unroll
                for (int r = 0; r < 4; ++r)
                    acc[rt][ct][r] += fsin_rad(30.f * (c[r] + bov));
            }
        }
    }

    // ---- store: non-temporal so the output stream doesn't evict the table from L2/L3 ----
    #pragma unroll
    for (int rt = 0; rt < 2; ++rt)
        #pragma unroll
        for (int r = 0; r < 4; ++r)
            #pragma unroll
            for (int ct = 0; ct < 8; ++ct) {
                int row = pbase + wv * 32 + rt * 16 + hi4 * 4 + r;
                __builtin_nontemporal_store(acc[rt][ct][r],
                                            &out[(size_t)row * 128 + ct * 16 + r15]);
            }
}

extern "C" void kernel_launch(void* const* d_in, const int* in_sizes, int n_in,
                              void* d_out, int out_size, void* d_ws, size_t ws_size,
                              hipStream_t stream) {
    const float* in_pos = (const float*)d_in[0];
    const float* table  = (const float*)d_in[1];
    const float* ffn    = (const float*)d_in[2];
    const float* W0     = (const float*)d_in[3];
    const float* b0     = (const float*)d_in[4];
    const float* Ws     = (const float*)d_in[5];
    const float* bs     = (const float*)d_in[6];
    const float* Wout   = (const float*)d_in[7];
    const float* bout   = (const float*)d_in[8];
    float* out = (float*)d_out;
    _Float16* ws = (_Float16*)d_ws;

    // ws layout: [0, 51200) f16 weights; table f16 at 65536 (128 KB offset), 32 MB
    const size_t need = 65536u * 2u + (size_t)NLVL * TSIZE * 8u * 2u;
    const bool f16tab = (ws_size >= need);
    _Float16* tab16 = ws + 65536;

    prep_weights<<<dim3(200), dim3(256), 0, stream>>>(Ws, Wout, ffn, ws);

    const int n = in_sizes[0] / 3;    // 524288
    if (f16tab) {
        prep_table<<<dim3((NLVL * TSIZE * 8) / 256), dim3(256), 0, stream>>>(table, tab16);
        ffb_main<true><<<dim3(n / MBLK), dim3(128), 0, stream>>>(
            in_pos, table, tab16, W0, b0, bs, bout, ws, out);
    } else {
        ffb_main<false><<<dim3(n / MBLK), dim3(128), 0, stream>>>(
            in_pos, table, tab16, W0, b0, bs, bout, ws, out);
    }
}

// Round 7
// 524.885 us; speedup vs baseline: 1.0419x; 1.0419x over previous
//
#include <hip/hip_runtime.h>
#include <cstdint>
#include <cstddef>

#define NLVL 4
#define TSIZE (1u << 19)
#define NH 64
#define NOUT 128
#define MBLK 64            // points per workgroup; 4 waves x 16 rows

typedef _Float16 f16x8 __attribute__((ext_vector_type(8)));
typedef _Float16 f16x2 __attribute__((ext_vector_type(2)));
typedef float f32x4 __attribute__((ext_vector_type(4)));
typedef unsigned short u16x8 __attribute__((ext_vector_type(8)));

__device__ __forceinline__ float fsin_rad(float x) {
    return __builtin_amdgcn_sinf(__builtin_amdgcn_fractf(x * 0.15915494309189535f));
}
__device__ __forceinline__ float fsin_rev(float r) {
    return __builtin_amdgcn_sinf(__builtin_amdgcn_fractf(r));
}
__device__ __forceinline__ unsigned short h2u(_Float16 h) {
    return __builtin_bit_cast(unsigned short, h);
}

// ---- prep kernel 1: transpose weights to [col][k] layout, f16, into d_ws ----
// ws layout (f16 elems): WsT 0..16384, WoutT 16384..49152, ffnT 49152..51200
__global__ void prep_weights(const float* __restrict__ Ws,
                             const float* __restrict__ Wout,
                             const float* __restrict__ ffn,
                             _Float16* __restrict__ ws)
{
    int i = blockIdx.x * 256 + threadIdx.x;
    _Float16* WsT = ws;            // [4][64 col][64 k]
    _Float16* WoT = ws + 16384;    // [4][128 col][64 k]
    _Float16* FfT = ws + 49152;    // [4][64 col][8 k]
    if (i < 16384) {
        int l = i >> 12, r = i & 4095, k = r >> 6, c = r & 63;
        WsT[l * 4096 + c * 64 + k] = (_Float16)Ws[i];
    } else if (i < 49152) {
        int j = i - 16384;
        int l = j >> 13, r = j & 8191, k = r >> 7, c = r & 127;
        WoT[l * 8192 + c * 64 + k] = (_Float16)Wout[j];
    } else if (i < 51200) {
        int j = i - 49152;
        int l = j >> 9, r = j & 511, k = r >> 6, c = r & 63;
        FfT[l * 512 + c * 8 + k] = (_Float16)ffn[j];
    }
}

// ---- prep kernel 2: table f32 -> f16 * 4096 (halves gather bytes; fits L2/L3) ----
__global__ __launch_bounds__(256) void prep_table(const float* __restrict__ table,
                                                  _Float16* __restrict__ tab16)
{
    int i = blockIdx.x * 256 + threadIdx.x;            // 16,777,216 elems
    float v = __builtin_nontemporal_load(table + i);   // stream, don't pollute L3
    tab16[i] = (_Float16)(v * 4096.f);
}

template <bool F16TAB>
__global__ __launch_bounds__(256, 6)
void ffb_main(const float* __restrict__ in_pos,
              const float* __restrict__ table,
              const _Float16* __restrict__ tab16,
              const float* __restrict__ W0,
              const float* __restrict__ b0,
              const float* __restrict__ bs,
              const float* __restrict__ bout,
              const _Float16* __restrict__ ws,
              float* __restrict__ out)
{
    // X plane: [64 rows][64 cols] f16, XOR-swizzled: idx = row*64 + (col ^ ((row&7)<<3))
    __shared__ __align__(16) unsigned short Xh[MBLK * NH];       // 8 KB
    __shared__ __align__(16) unsigned short gS[NLVL][MBLK][8];   // 4 KB, g scaled by 4096

    const int tid = threadIdx.x;
    const int pbase = blockIdx.x * MBLK;

    // ---------- stage 1: one (point, level) gather per thread + layer0 ----------
    {
        const int p = tid & (MBLK - 1);
        const int lv = tid >> 6;                   // 4 waves = 4 levels
        const float px = in_pos[3 * (pbase + p) + 0];
        const float py = in_pos[3 * (pbase + p) + 1];
        const float pz = in_pos[3 * (pbase + p) + 2];
        const float qx = (px + 1.f) * 0.5f, qy = (py + 1.f) * 0.5f, qz = (pz + 1.f) * 0.5f;
        const uint32_t P1 = 2654435761u, P2 = 805459861u;

        const float res = (float)(16 << lv);
        float gx = qx * res, gy = qy * res, gz = qz * res;
        float fx0 = floorf(gx), fy0 = floorf(gy), fz0 = floorf(gz);
        float fx = gx - fx0, fy = gy - fy0, fz = gz - fz0;
        uint32_t ux = (uint32_t)fx0, uy = (uint32_t)fy0, uz = (uint32_t)fz0;
        uint32_t hx0 = ux, hx1 = ux + 1u;
        uint32_t hy0 = uy * P1, hy1 = hy0 + P1;
        uint32_t hz0 = uz * P2, hz1 = hz0 + P2;

        uint32_t hh[8];
        float    wgt[8];
        #pragma unroll
        for (int c = 0; c < 8; ++c) {
            hh[c] = (((c & 4) ? hx1 : hx0) ^ ((c & 2) ? hy1 : hy0)
                     ^ ((c & 1) ? hz1 : hz0)) & (TSIZE - 1u);
            wgt[c] = ((c & 4) ? fx : 1.f - fx) * ((c & 2) ? fy : 1.f - fy)
                   * ((c & 1) ? fz : 1.f - fz);
        }

        if (F16TAB) {
            const _Float16* tl = tab16 + (size_t)lv * TSIZE * 8;
            u16x8 vv[8];
            #pragma unroll
            for (int c = 0; c < 8; ++c)
                vv[c] = *(const u16x8*)(tl + (size_t)hh[c] * 8);
            f16x2 acc2[4];
            #pragma unroll
            for (int q = 0; q < 4; ++q) acc2[q] = (f16x2){(_Float16)0.f, (_Float16)0.f};
            #pragma unroll
            for (int c = 0; c < 8; ++c) {
                _Float16 wh = (_Float16)wgt[c];
                f16x2 ww = {wh, wh};
                const f16x2* vp = (const f16x2*)&vv[c];
                #pragma unroll
                for (int q = 0; q < 4; ++q) acc2[q] = acc2[q] + ww * vp[q];  // v_pk_fma_f16
            }
            *(u16x8*)&gS[lv][p][0] = *(u16x8*)&acc2[0];
        } else {
            const float* tl = table + (size_t)lv * TSIZE * 8;
            float g[8];
            #pragma unroll
            for (int q = 0; q < 8; ++q) g[q] = 0.f;
            #pragma unroll
            for (int c = 0; c < 8; ++c) {
                const float4* fp = (const float4*)(tl + (size_t)hh[c] * 8);
                float4 va = fp[0], vb = fp[1];
                float w = wgt[c];
                g[0] = fmaf(w, va.x, g[0]); g[1] = fmaf(w, va.y, g[1]);
                g[2] = fmaf(w, va.z, g[2]); g[3] = fmaf(w, va.w, g[3]);
                g[4] = fmaf(w, vb.x, g[4]); g[5] = fmaf(w, vb.y, g[5]);
                g[6] = fmaf(w, vb.z, g[6]); g[7] = fmaf(w, vb.w, g[7]);
            }
            u16x8 gv;
            #pragma unroll
            for (int q = 0; q < 8; ++q)
                gv[q] = h2u((_Float16)(g[q] * 4096.f));
            *(u16x8*)&gS[lv][p][0] = gv;
        }

        // layer0: x0 = sin(30*(pos@W0 + b0)); this thread does 16 cols of point p
        const int ch = (tid >> 6) * 16;
        #pragma unroll 4
        for (int c = ch; c < ch + 16; c += 2) {
            float a0 = b0[c]     + px * W0[c]     + py * W0[64 + c] + pz * W0[128 + c];
            float a1 = b0[c + 1] + px * W0[c + 1] + py * W0[65 + c] + pz * W0[129 + c];
            _Float16 h0 = (_Float16)fsin_rad(30.f * a0);
            _Float16 h1 = (_Float16)fsin_rad(30.f * a1);
            int idx = p * 64 + (c ^ ((p & 7) << 3));
            *(unsigned int*)&Xh[idx] = (unsigned int)h2u(h0) | ((unsigned int)h2u(h1) << 16);
        }
    }
    __syncthreads();
    // After this barrier: wave wv exclusively owns X-plane rows [wv*16, wv*16+16). No more barriers.

    const int lane = tid & 63;
    const int wv = tid >> 6;
    const int r15 = lane & 15;
    const int hi4 = lane >> 4;
    const char* Xhb = (const char*)Xh;

    // A-fragments: lane -> row = wv*16 + (lane&15), k = kb*32 + (lane>>4)*8 + j
    f16x8 Axh[2];
    auto loadA = [&]() {
        #pragma unroll
        for (int kb = 0; kb < 2; ++kb) {
            int row = wv * 16 + r15;
            int off = row * 128 + ((kb * 64 + hi4 * 16) ^ ((row & 7) << 4));
            Axh[kb] = *(const f16x8*)(Xhb + off);
        }
    };
    loadA();

    float acc[8][4];
    #pragma unroll
    for (int ct = 0; ct < 8; ++ct)
        #pragma unroll
        for (int r = 0; r < 4; ++r) acc[ct][r] = 0.f;

    const _Float16* WsT = ws;
    const _Float16* WoT = ws + 16384;
    const _Float16* FfT = ws + 49152;

    #pragma unroll 1
    for (int lvl = 0; lvl < NLVL; ++lvl) {
        // g A-frag: only lanes 0-15 carry k<8; rest zero
        f16x8 Ag;
        {
            f16x8 z;
            #pragma unroll
            for (int q = 0; q < 8; ++q) z[q] = (_Float16)0.f;
            if (lane < 16)
                z = *(const f16x8*)&gS[lvl][wv * 16 + lane][0];
            Ag = z;
        }

        // ---- phase B: xn = sin(30*(X@Ws + bs)) + sin(2pi*(g@ffn)) ----
        #pragma unroll
        for (int ct = 0; ct < 4; ++ct) {
            const _Float16* bp = WsT + lvl * 4096 + (ct * 16 + r15) * 64 + hi4 * 8;
            f16x8 B0 = *(const f16x8*)bp;          // kb = 0
            f16x8 B1 = *(const f16x8*)(bp + 32);   // kb = 1
            f16x8 Bf;
            #pragma unroll
            for (int q = 0; q < 8; ++q) Bf[q] = (_Float16)0.f;
            if (lane < 16)
                Bf = *(const f16x8*)(FfT + lvl * 512 + (ct * 16 + r15) * 8);
            float bsv = bs[lvl * 64 + ct * 16 + r15];

            f32x4 c1 = {0.f, 0.f, 0.f, 0.f};
            c1 = __builtin_amdgcn_mfma_f32_16x16x32_f16(Axh[0], B0, c1, 0, 0, 0);
            c1 = __builtin_amdgcn_mfma_f32_16x16x32_f16(Axh[1], B1, c1, 0, 0, 0);
            f32x4 c2 = {0.f, 0.f, 0.f, 0.f};
            c2 = __builtin_amdgcn_mfma_f32_16x16x32_f16(Ag, Bf, c2, 0, 0, 0);
            #pragma unroll
            for (int r = 0; r < 4; ++r) {
                int row = wv * 16 + hi4 * 4 + r;
                int col = ct * 16 + r15;
                float xn = fsin_rad(30.f * (c1[r] + bsv))
                         + fsin_rev(c2[r] * 0.000244140625f);  // /4096
                int idx = row * 64 + (col ^ ((row & 7) << 3));
                Xh[idx] = h2u((_Float16)xn);
            }
        }
        loadA();   // new x -> A-frags (also reused by next level's phase B)

        // ---- phase C: out += sin(30*(x@Wout + bout)) ----
        #pragma unroll
        for (int ct = 0; ct < 8; ++ct) {
            const _Float16* bp = WoT + lvl * 8192 + (ct * 16 + r15) * 64 + hi4 * 8;
            f16x8 B0 = *(const f16x8*)bp;
            f16x8 B1 = *(const f16x8*)(bp + 32);
            float bov = bout[lvl * 128 + ct * 16 + r15];
            f32x4 c = {0.f, 0.f, 0.f, 0.f};
            c = __builtin_amdgcn_mfma_f32_16x16x32_f16(Axh[0], B0, c, 0, 0, 0);
            c = __builtin_amdgcn_mfma_f32_16x16x32_f16(Axh[1], B1, c, 0, 0, 0);
            #pragma unroll
            for (int r = 0; r < 4; ++r)
                acc[ct][r] += fsin_rad(30.f * (c[r] + bov));
        }
    }

    // ---- store: non-temporal so the output stream doesn't evict the table from L2/L3 ----
    #pragma unroll
    for (int r = 0; r < 4; ++r)
        #pragma unroll
        for (int ct = 0; ct < 8; ++ct) {
            int row = pbase + wv * 16 + hi4 * 4 + r;
            __builtin_nontemporal_store(acc[ct][r],
                                        &out[(size_t)row * 128 + ct * 16 + r15]);
        }
}

extern "C" void kernel_launch(void* const* d_in, const int* in_sizes, int n_in,
                              void* d_out, int out_size, void* d_ws, size_t ws_size,
                              hipStream_t stream) {
    const float* in_pos = (const float*)d_in[0];
    const float* table  = (const float*)d_in[1];
    const float* ffn    = (const float*)d_in[2];
    const float* W0     = (const float*)d_in[3];
    const float* b0     = (const float*)d_in[4];
    const float* Ws     = (const float*)d_in[5];
    const float* bs     = (const float*)d_in[6];
    const float* Wout   = (const float*)d_in[7];
    const float* bout   = (const float*)d_in[8];
    float* out = (float*)d_out;
    _Float16* ws = (_Float16*)d_ws;

    // ws layout: [0, 51200) f16 weights; table f16 at 65536 (128 KB offset), 32 MB
    const size_t need = 65536u * 2u + (size_t)NLVL * TSIZE * 8u * 2u;
    const bool f16tab = (ws_size >= need);
    _Float16* tab16 = ws + 65536;

    prep_weights<<<dim3(200), dim3(256), 0, stream>>>(Ws, Wout, ffn, ws);

    const int n = in_sizes[0] / 3;    // 524288
    if (f16tab) {
        prep_table<<<dim3((NLVL * TSIZE * 8) / 256), dim3(256), 0, stream>>>(table, tab16);
        ffb_main<true><<<dim3(n / MBLK), dim3(256), 0, stream>>>(
            in_pos, table, tab16, W0, b0, bs, bout, ws, out);
    } else {
        ffb_main<false><<<dim3(n / MBLK), dim3(256), 0, stream>>>(
            in_pos, table, tab16, W0, b0, bs, bout, ws, out);
    }
}

// Round 8
// 515.087 us; speedup vs baseline: 1.0618x; 1.0190x over previous
//
#include <hip/hip_runtime.h>
#include <cstdint>
#include <cstddef>

#define NLVL 4
#define TSIZE (1u << 19)
#define NH 64
#define NOUT 128
#define MBLK 64            // points per workgroup; 8 waves: (4 row-groups) x (2 col-halves)

typedef _Float16 f16x8 __attribute__((ext_vector_type(8)));
typedef _Float16 f16x2 __attribute__((ext_vector_type(2)));
typedef float f32x4 __attribute__((ext_vector_type(4)));
typedef unsigned short u16x8 __attribute__((ext_vector_type(8)));

__device__ __forceinline__ float fsin_rad(float x) {
    return __builtin_amdgcn_sinf(__builtin_amdgcn_fractf(x * 0.15915494309189535f));
}
__device__ __forceinline__ float fsin_rev(float r) {
    return __builtin_amdgcn_sinf(__builtin_amdgcn_fractf(r));
}
__device__ __forceinline__ unsigned short h2u(_Float16 h) {
    return __builtin_bit_cast(unsigned short, h);
}

// ---- prep kernel 1: transpose weights to [col][k] layout, f16, into d_ws ----
// ws layout (f16 elems): WsT 0..16384, WoutT 16384..49152, ffnT 49152..51200
__global__ void prep_weights(const float* __restrict__ Ws,
                             const float* __restrict__ Wout,
                             const float* __restrict__ ffn,
                             _Float16* __restrict__ ws)
{
    int i = blockIdx.x * 256 + threadIdx.x;
    _Float16* WsT = ws;            // [4][64 col][64 k]
    _Float16* WoT = ws + 16384;    // [4][128 col][64 k]
    _Float16* FfT = ws + 49152;    // [4][64 col][8 k]
    if (i < 16384) {
        int l = i >> 12, r = i & 4095, k = r >> 6, c = r & 63;
        WsT[l * 4096 + c * 64 + k] = (_Float16)Ws[i];
    } else if (i < 49152) {
        int j = i - 16384;
        int l = j >> 13, r = j & 8191, k = r >> 7, c = r & 127;
        WoT[l * 8192 + c * 64 + k] = (_Float16)Wout[j];
    } else if (i < 51200) {
        int j = i - 49152;
        int l = j >> 9, r = j & 511, k = r >> 6, c = r & 63;
        FfT[l * 512 + c * 8 + k] = (_Float16)ffn[j];
    }
}

// ---- prep kernel 2: table f32 -> f16 * 4096 (halves gather bytes; fits L2/L3) ----
__global__ __launch_bounds__(256) void prep_table(const float* __restrict__ table,
                                                  _Float16* __restrict__ tab16)
{
    int i = blockIdx.x * 256 + threadIdx.x;            // 16,777,216 elems
    float v = __builtin_nontemporal_load(table + i);   // stream, don't pollute L3
    tab16[i] = (_Float16)(v * 4096.f);
}

template <bool F16TAB>
__global__ __launch_bounds__(512, 4)
void ffb_main(const float* __restrict__ in_pos,
              const float* __restrict__ table,
              const _Float16* __restrict__ tab16,
              const float* __restrict__ W0,
              const float* __restrict__ b0,
              const float* __restrict__ bs,
              const float* __restrict__ bout,
              const _Float16* __restrict__ ws,
              float* __restrict__ out)
{
    // X plane: [64 rows][64 cols] f16, XOR-swizzled: idx = row*64 + (col ^ ((row&7)<<3))
    __shared__ __align__(16) unsigned short Xh[MBLK * NH];       // 8 KB
    __shared__ __align__(16) unsigned short gS[NLVL][MBLK][8];   // 4 KB, g scaled by 4096

    const int tid = threadIdx.x;
    const int pbase = blockIdx.x * MBLK;
    const int p = tid & (MBLK - 1);

    const float px = in_pos[3 * (pbase + p) + 0];
    const float py = in_pos[3 * (pbase + p) + 1];
    const float pz = in_pos[3 * (pbase + p) + 2];

    // ---------- stage 1: threads 0-255 gather one (point, level) each ----------
    if (tid < 256) {
        const int lv = tid >> 6;
        const float qx = (px + 1.f) * 0.5f, qy = (py + 1.f) * 0.5f, qz = (pz + 1.f) * 0.5f;
        const uint32_t P1 = 2654435761u, P2 = 805459861u;

        const float res = (float)(16 << lv);
        float gx = qx * res, gy = qy * res, gz = qz * res;
        float fx0 = floorf(gx), fy0 = floorf(gy), fz0 = floorf(gz);
        float fx = gx - fx0, fy = gy - fy0, fz = gz - fz0;
        uint32_t ux = (uint32_t)fx0, uy = (uint32_t)fy0, uz = (uint32_t)fz0;
        uint32_t hx0 = ux, hx1 = ux + 1u;
        uint32_t hy0 = uy * P1, hy1 = hy0 + P1;
        uint32_t hz0 = uz * P2, hz1 = hz0 + P2;

        uint32_t hh[8];
        float    wgt[8];
        #pragma unroll
        for (int c = 0; c < 8; ++c) {
            hh[c] = (((c & 4) ? hx1 : hx0) ^ ((c & 2) ? hy1 : hy0)
                     ^ ((c & 1) ? hz1 : hz0)) & (TSIZE - 1u);
            wgt[c] = ((c & 4) ? fx : 1.f - fx) * ((c & 2) ? fy : 1.f - fy)
                   * ((c & 1) ? fz : 1.f - fz);
        }

        if (F16TAB) {
            const _Float16* tl = tab16 + (size_t)lv * TSIZE * 8;
            u16x8 vv[8];
            #pragma unroll
            for (int c = 0; c < 8; ++c)
                vv[c] = *(const u16x8*)(tl + (size_t)hh[c] * 8);
            f16x2 acc2[4];
            #pragma unroll
            for (int q = 0; q < 4; ++q) acc2[q] = (f16x2){(_Float16)0.f, (_Float16)0.f};
            #pragma unroll
            for (int c = 0; c < 8; ++c) {
                _Float16 wh = (_Float16)wgt[c];
                f16x2 ww = {wh, wh};
                const f16x2* vp = (const f16x2*)&vv[c];
                #pragma unroll
                for (int q = 0; q < 4; ++q) acc2[q] = acc2[q] + ww * vp[q];  // v_pk_fma_f16
            }
            *(u16x8*)&gS[lv][p][0] = *(u16x8*)&acc2[0];
        } else {
            const float* tl = table + (size_t)lv * TSIZE * 8;
            float g[8];
            #pragma unroll
            for (int q = 0; q < 8; ++q) g[q] = 0.f;
            #pragma unroll
            for (int c = 0; c < 8; ++c) {
                const float4* fp = (const float4*)(tl + (size_t)hh[c] * 8);
                float4 va = fp[0], vb = fp[1];
                float w = wgt[c];
                g[0] = fmaf(w, va.x, g[0]); g[1] = fmaf(w, va.y, g[1]);
                g[2] = fmaf(w, va.z, g[2]); g[3] = fmaf(w, va.w, g[3]);
                g[4] = fmaf(w, vb.x, g[4]); g[5] = fmaf(w, vb.y, g[5]);
                g[6] = fmaf(w, vb.z, g[6]); g[7] = fmaf(w, vb.w, g[7]);
            }
            u16x8 gv;
            #pragma unroll
            for (int q = 0; q < 8; ++q)
                gv[q] = h2u((_Float16)(g[q] * 4096.f));
            *(u16x8*)&gS[lv][p][0] = gv;
        }
    }

    // layer0: x0 = sin(30*(pos@W0 + b0)); each of 512 threads does 8 cols of its point
    {
        const int ch = (tid >> 6) * 8;
        #pragma unroll 4
        for (int c = ch; c < ch + 8; c += 2) {
            float a0 = b0[c]     + px * W0[c]     + py * W0[64 + c] + pz * W0[128 + c];
            float a1 = b0[c + 1] + px * W0[c + 1] + py * W0[65 + c] + pz * W0[129 + c];
            _Float16 h0 = (_Float16)fsin_rad(30.f * a0);
            _Float16 h1 = (_Float16)fsin_rad(30.f * a1);
            int idx = p * 64 + (c ^ ((p & 7) << 3));
            *(unsigned int*)&Xh[idx] = (unsigned int)h2u(h0) | ((unsigned int)h2u(h1) << 16);
        }
    }
    __syncthreads();

    const int lane = tid & 63;
    const int wv = tid >> 6;
    const int g  = wv >> 1;           // row-group: rows [16g, 16g+16)
    const int h  = wv & 1;            // column half
    const int r15 = lane & 15;
    const int hi4 = lane >> 4;
    const char* Xhb = (const char*)Xh;

    // A-fragments: lane -> row = g*16 + (lane&15), k = kb*32 + (lane>>4)*8 + j
    f16x8 Axh[2];
    auto loadA = [&]() {
        #pragma unroll
        for (int kb = 0; kb < 2; ++kb) {
            int row = g * 16 + r15;
            int off = row * 128 + ((kb * 64 + hi4 * 16) ^ ((row & 7) << 4));
            Axh[kb] = *(const f16x8*)(Xhb + off);
        }
    };
    loadA();
    __syncthreads();   // all waves hold A-frags before anyone overwrites X

    float acc[4][4];
    #pragma unroll
    for (int ct = 0; ct < 4; ++ct)
        #pragma unroll
        for (int r = 0; r < 4; ++r) acc[ct][r] = 0.f;

    const _Float16* WsT = ws;
    const _Float16* WoT = ws + 16384;
    const _Float16* FfT = ws + 49152;

    #pragma unroll 1
    for (int lvl = 0; lvl < NLVL; ++lvl) {
        // g A-frag: only lanes 0-15 carry k<8; rest zero
        f16x8 Ag;
        {
            f16x8 z;
            #pragma unroll
            for (int q = 0; q < 8; ++q) z[q] = (_Float16)0.f;
            if (lane < 16)
                z = *(const f16x8*)&gS[lvl][g * 16 + lane][0];
            Ag = z;
        }

        // ---- phase B: this wave updates X rows [16g,16g+16), col half h ----
        #pragma unroll
        for (int ct2 = 0; ct2 < 2; ++ct2) {
            const int ct = 2 * h + ct2;
            const _Float16* bp = WsT + lvl * 4096 + (ct * 16 + r15) * 64 + hi4 * 8;
            f16x8 B0 = *(const f16x8*)bp;          // kb = 0
            f16x8 B1 = *(const f16x8*)(bp + 32);   // kb = 1
            f16x8 Bf;
            #pragma unroll
            for (int q = 0; q < 8; ++q) Bf[q] = (_Float16)0.f;
            if (lane < 16)
                Bf = *(const f16x8*)(FfT + lvl * 512 + (ct * 16 + r15) * 8);
            float bsv = bs[lvl * 64 + ct * 16 + r15];

            f32x4 c1 = {0.f, 0.f, 0.f, 0.f};
            c1 = __builtin_amdgcn_mfma_f32_16x16x32_f16(Axh[0], B0, c1, 0, 0, 0);
            c1 = __builtin_amdgcn_mfma_f32_16x16x32_f16(Axh[1], B1, c1, 0, 0, 0);
            f32x4 c2 = {0.f, 0.f, 0.f, 0.f};
            c2 = __builtin_amdgcn_mfma_f32_16x16x32_f16(Ag, Bf, c2, 0, 0, 0);
            #pragma unroll
            for (int r = 0; r < 4; ++r) {
                int row = g * 16 + hi4 * 4 + r;
                int col = ct * 16 + r15;
                float xn = fsin_rad(30.f * (c1[r] + bsv))
                         + fsin_rev(c2[r] * 0.000244140625f);  // /4096
                int idx = row * 64 + (col ^ ((row & 7) << 3));
                Xh[idx] = h2u((_Float16)xn);
            }
        }
        __syncthreads();   // X fully updated by both col-halves
        loadA();           // new x -> A-frags
        __syncthreads();   // everyone holds frags; next level may overwrite X

        // ---- phase C: out += sin(30*(x@Wout + bout)), col half h ----
        #pragma unroll
        for (int ct2 = 0; ct2 < 4; ++ct2) {
            const int ct = 4 * h + ct2;
            const _Float16* bp = WoT + lvl * 8192 + (ct * 16 + r15) * 64 + hi4 * 8;
            f16x8 B0 = *(const f16x8*)bp;
            f16x8 B1 = *(const f16x8*)(bp + 32);
            float bov = bout[lvl * 128 + ct * 16 + r15];
            f32x4 c = {0.f, 0.f, 0.f, 0.f};
            c = __builtin_amdgcn_mfma_f32_16x16x32_f16(Axh[0], B0, c, 0, 0, 0);
            c = __builtin_amdgcn_mfma_f32_16x16x32_f16(Axh[1], B1, c, 0, 0, 0);
            #pragma unroll
            for (int r = 0; r < 4; ++r)
                acc[ct2][r] += fsin_rad(30.f * (c[r] + bov));
        }
    }

    // ---- store: non-temporal so the output stream doesn't evict the table from L2/L3 ----
    #pragma unroll
    for (int r = 0; r < 4; ++r)
        #pragma unroll
        for (int ct2 = 0; ct2 < 4; ++ct2) {
            int row = pbase + g * 16 + hi4 * 4 + r;
            int col = (4 * h + ct2) * 16 + r15;
            __builtin_nontemporal_store(acc[ct2][r], &out[(size_t)row * 128 + col]);
        }
}

extern "C" void kernel_launch(void* const* d_in, const int* in_sizes, int n_in,
                              void* d_out, int out_size, void* d_ws, size_t ws_size,
                              hipStream_t stream) {
    const float* in_pos = (const float*)d_in[0];
    const float* table  = (const float*)d_in[1];
    const float* ffn    = (const float*)d_in[2];
    const float* W0     = (const float*)d_in[3];
    const float* b0     = (const float*)d_in[4];
    const float* Ws     = (const float*)d_in[5];
    const float* bs     = (const float*)d_in[6];
    const float* Wout   = (const float*)d_in[7];
    const float* bout   = (const float*)d_in[8];
    float* out = (float*)d_out;
    _Float16* ws = (_Float16*)d_ws;

    // ws layout: [0, 51200) f16 weights; table f16 at 65536 (128 KB offset), 32 MB
    const size_t need = 65536u * 2u + (size_t)NLVL * TSIZE * 8u * 2u;
    const bool f16tab = (ws_size >= need);
    _Float16* tab16 = ws + 65536;

    prep_weights<<<dim3(200), dim3(256), 0, stream>>>(Ws, Wout, ffn, ws);

    const int n = in_sizes[0] / 3;    // 524288
    if (f16tab) {
        prep_table<<<dim3((NLVL * TSIZE * 8) / 256), dim3(256), 0, stream>>>(table, tab16);
        ffb_main<true><<<dim3(n / MBLK), dim3(512), 0, stream>>>(
            in_pos, table, tab16, W0, b0, bs, bout, ws, out);
    } else {
        ffb_main<false><<<dim3(n / MBLK), dim3(512), 0, stream>>>(
            in_pos, table, tab16, W0, b0, bs, bout, ws, out);
    }
}

// Round 9
// 336.066 us; speedup vs baseline: 1.6274x; 1.5327x over previous
//
#include <hip/hip_runtime.h>
#include <cstdint>
#include <cstddef>

#define NLVL 4
#define TSIZE (1u << 19)
#define NH 64
#define NOUT 128
#define MBLK 64            // points per workgroup; 4 waves x 16 points, independent after stage 1

typedef _Float16 f16x8 __attribute__((ext_vector_type(8)));
typedef _Float16 f16x2 __attribute__((ext_vector_type(2)));
typedef float f32x4 __attribute__((ext_vector_type(4)));
typedef unsigned short u16x8 __attribute__((ext_vector_type(8)));
typedef unsigned int u32x4 __attribute__((ext_vector_type(4)));

__device__ __forceinline__ float fsin_rad(float x) {
    return __builtin_amdgcn_sinf(__builtin_amdgcn_fractf(x * 0.15915494309189535f));
}
__device__ __forceinline__ float fsin_rev(float r) {
    return __builtin_amdgcn_sinf(__builtin_amdgcn_fractf(r));
}
__device__ __forceinline__ unsigned short h2u(_Float16 h) {
    return __builtin_bit_cast(unsigned short, h);
}
__device__ __forceinline__ unsigned int pk16(float a, float b) {
    return __builtin_bit_cast(unsigned int, __builtin_amdgcn_cvt_pkrtz(a, b));
}

// ---- prep kernel 1: weights into MFMA-fragment order, f16, into d_ws ----
// ws f16 layout: WsT [0,16384)   A-frag order: lvl*4096 + c*64 + k
//                FfT [16384,18432) A-frag order: lvl*512 + c*8 + k
//                WoB [18432,51200) B-frag order: ((lvl*8+ct)*2+kb)*512 + h*128 + r15*8 + j
__global__ void prep_weights(const float* __restrict__ Ws,
                             const float* __restrict__ Wout,
                             const float* __restrict__ ffn,
                             _Float16* __restrict__ ws)
{
    int i = blockIdx.x * 256 + threadIdx.x;
    if (i < 16384) {                       // Ws [4][64k][64c]
        int l = i >> 12, r = i & 4095, k = r >> 6, c = r & 63;
        ws[l * 4096 + c * 64 + k] = (_Float16)Ws[i];
    } else if (i < 18432) {                // ffn [4][8k][64c]
        int j = i - 16384;
        int l = j >> 9, r = j & 511, k = r >> 6, c = r & 63;
        ws[16384 + l * 512 + c * 8 + k] = (_Float16)ffn[j];
    } else if (i < 51200) {                // Wout [4][64k][128c] -> B-frag order
        int j = i - 18432;
        int l = j >> 13, rem = j & 8191, k = rem >> 7, c = rem & 127;
        int ct = c >> 4, r15 = c & 15, kb = k >> 5, h = (k >> 3) & 3, jj = k & 7;
        ws[18432 + (((l * 8 + ct) * 2 + kb) * 512) + h * 128 + r15 * 8 + jj] =
            (_Float16)Wout[j];
    }
}

// ---- prep kernel 2: table f32 -> f16 * 4096 (halves gather bytes) ----
__global__ __launch_bounds__(256) void prep_table(const float* __restrict__ table,
                                                  _Float16* __restrict__ tab16)
{
    int i = blockIdx.x * 256 + threadIdx.x;            // 16,777,216 elems
    float v = __builtin_nontemporal_load(table + i);
    tab16[i] = (_Float16)(v * 4096.f);
}

template <bool F16TAB>
__global__ __launch_bounds__(256, 3)
void ffb_main(const float* __restrict__ in_pos,
              const float* __restrict__ table,
              const _Float16* __restrict__ tab16,
              const float* __restrict__ W0,
              const float* __restrict__ b0,
              const float* __restrict__ bs,
              const float* __restrict__ bout,
              const _Float16* __restrict__ ws,
              float* __restrict__ out)
{
    // X staging for layer0 only: [64 rows][64 cols] f16, XOR-swizzled
    __shared__ __align__(16) unsigned short Xh[MBLK * NH];       // 8 KB
    __shared__ __align__(16) unsigned short gS[NLVL][MBLK][8];   // 4 KB, g scaled by 4096

    const int tid = threadIdx.x;
    const int pbase = blockIdx.x * MBLK;
    const int p = tid & (MBLK - 1);

    const float px = in_pos[3 * (pbase + p) + 0];
    const float py = in_pos[3 * (pbase + p) + 1];
    const float pz = in_pos[3 * (pbase + p) + 2];

    // ---------- stage 1: each thread gathers one (point, level) ----------
    {
        const int lv = tid >> 6;
        const float qx = (px + 1.f) * 0.5f, qy = (py + 1.f) * 0.5f, qz = (pz + 1.f) * 0.5f;
        const uint32_t P1 = 2654435761u, P2 = 805459861u;

        const float res = (float)(16 << lv);
        float gx = qx * res, gy = qy * res, gz = qz * res;
        float fx0 = floorf(gx), fy0 = floorf(gy), fz0 = floorf(gz);
        float fx = gx - fx0, fy = gy - fy0, fz = gz - fz0;
        uint32_t ux = (uint32_t)fx0, uy = (uint32_t)fy0, uz = (uint32_t)fz0;
        uint32_t hx0 = ux, hx1 = ux + 1u;
        uint32_t hy0 = uy * P1, hy1 = hy0 + P1;
        uint32_t hz0 = uz * P2, hz1 = hz0 + P2;

        uint32_t hh[8];
        float    wgt[8];
        #pragma unroll
        for (int c = 0; c < 8; ++c) {
            hh[c] = (((c & 4) ? hx1 : hx0) ^ ((c & 2) ? hy1 : hy0)
                     ^ ((c & 1) ? hz1 : hz0)) & (TSIZE - 1u);
            wgt[c] = ((c & 4) ? fx : 1.f - fx) * ((c & 2) ? fy : 1.f - fy)
                   * ((c & 1) ? fz : 1.f - fz);
        }

        if (F16TAB) {
            const _Float16* tl = tab16 + (size_t)lv * TSIZE * 8;
            u16x8 vv[8];
            #pragma unroll
            for (int c = 0; c < 8; ++c)
                vv[c] = *(const u16x8*)(tl + (size_t)hh[c] * 8);
            f16x2 acc2[4];
            #pragma unroll
            for (int q = 0; q < 4; ++q) acc2[q] = (f16x2){(_Float16)0.f, (_Float16)0.f};
            #pragma unroll
            for (int c = 0; c < 8; ++c) {
                _Float16 wh = (_Float16)wgt[c];
                f16x2 ww = {wh, wh};
                const f16x2* vp = (const f16x2*)&vv[c];
                #pragma unroll
                for (int q = 0; q < 4; ++q) acc2[q] = acc2[q] + ww * vp[q];
            }
            *(u16x8*)&gS[lv][p][0] = *(u16x8*)&acc2[0];
        } else {
            const float* tl = table + (size_t)lv * TSIZE * 8;
            float g[8];
            #pragma unroll
            for (int q = 0; q < 8; ++q) g[q] = 0.f;
            #pragma unroll
            for (int c = 0; c < 8; ++c) {
                const float4* fp = (const float4*)(tl + (size_t)hh[c] * 8);
                float4 va = fp[0], vb = fp[1];
                float w = wgt[c];
                g[0] = fmaf(w, va.x, g[0]); g[1] = fmaf(w, va.y, g[1]);
                g[2] = fmaf(w, va.z, g[2]); g[3] = fmaf(w, va.w, g[3]);
                g[4] = fmaf(w, vb.x, g[4]); g[5] = fmaf(w, vb.y, g[5]);
                g[6] = fmaf(w, vb.z, g[6]); g[7] = fmaf(w, vb.w, g[7]);
            }
            u16x8 gv;
            #pragma unroll
            for (int q = 0; q < 8; ++q)
                gv[q] = h2u((_Float16)(g[q] * 4096.f));
            *(u16x8*)&gS[lv][p][0] = gv;
        }

        // layer0: x0 = sin(30*(pos@W0 + b0)); 16 cols of this thread's point
        const int ch = (tid >> 6) * 16;
        #pragma unroll 4
        for (int c = ch; c < ch + 16; c += 2) {
            float a0 = b0[c]     + px * W0[c]     + py * W0[64 + c] + pz * W0[128 + c];
            float a1 = b0[c + 1] + px * W0[c + 1] + py * W0[65 + c] + pz * W0[129 + c];
            _Float16 h0 = (_Float16)fsin_rad(30.f * a0);
            _Float16 h1 = (_Float16)fsin_rad(30.f * a1);
            int idx = p * 64 + (c ^ ((p & 7) << 3));
            *(unsigned int*)&Xh[idx] = (unsigned int)h2u(h0) | ((unsigned int)h2u(h1) << 16);
        }
    }
    __syncthreads();   // the ONLY barrier

    const int lane = tid & 63;
    const int wv = tid >> 6;          // wave owns points [16*wv, 16*wv+16)
    const int r15 = lane & 15;
    const int hi4 = lane >> 4;

    // X state as B-fragments: col(point)=lane&15, k(feature)=kb*32+hi4*8+j
    f16x8 Xb[2];
    {
        const char* Xhb = (const char*)Xh;
        #pragma unroll
        for (int kb = 0; kb < 2; ++kb) {
            int row = wv * 16 + r15;
            int off = row * 128 + ((kb * 64 + hi4 * 16) ^ ((row & 7) << 4));
            Xb[kb] = *(const f16x8*)(Xhb + off);
        }
    }

    // bpermute indices (byte addressing, lane*4)
    const int idxA = ((lane & 16) << 3) + r15 * 4;   // src = 32*(h&1) + r15
    const int idxB = idxA + 64;                      // src += 16
    const bool hiHalf = (lane & 32) != 0;            // h >= 2

    f16x2 accP[8][2];
    #pragma unroll
    for (int ct = 0; ct < 8; ++ct)
        #pragma unroll
        for (int s = 0; s < 2; ++s) accP[ct][s] = (f16x2){(_Float16)0.f, (_Float16)0.f};

    const _Float16* WsT = ws;
    const _Float16* FfT = ws + 16384;
    const _Float16* WoB = ws + 18432;

    #pragma unroll 1
    for (int lvl = 0; lvl < NLVL; ++lvl) {
        // g as B-frag: col(point)=r15, k(feat 0..7) -> only hi4==0 lanes nonzero
        f16x8 gB;
        {
            f16x8 z;
            #pragma unroll
            for (int q = 0; q < 8; ++q) z[q] = (_Float16)0.f;
            if (lane < 16)
                z = *(const f16x8*)&gS[lvl][wv * 16 + lane][0];
            gB = z;
        }

        // ---- phase B: C1 = Ws^T(A) x X(B); C col=point=lane&15, row=feat=hi4*4+r ----
        unsigned int P[4][2];
        #pragma unroll
        for (int ct = 0; ct < 4; ++ct) {
            const _Float16* ap = WsT + lvl * 4096 + (ct * 16 + r15) * 64 + hi4 * 8;
            f16x8 A0 = *(const f16x8*)ap;          // kb = 0
            f16x8 A1 = *(const f16x8*)(ap + 32);   // kb = 1
            f16x8 Af;
            #pragma unroll
            for (int q = 0; q < 8; ++q) Af[q] = (_Float16)0.f;
            if (lane < 16)
                Af = *(const f16x8*)(FfT + lvl * 512 + (ct * 16 + lane) * 8);
            float4 bs4 = *(const float4*)&bs[lvl * 64 + ct * 16 + hi4 * 4];

            f32x4 c1 = {0.f, 0.f, 0.f, 0.f};
            c1 = __builtin_amdgcn_mfma_f32_16x16x32_f16(A0, Xb[0], c1, 0, 0, 0);
            c1 = __builtin_amdgcn_mfma_f32_16x16x32_f16(A1, Xb[1], c1, 0, 0, 0);
            f32x4 c2 = {0.f, 0.f, 0.f, 0.f};
            c2 = __builtin_amdgcn_mfma_f32_16x16x32_f16(Af, gB, c2, 0, 0, 0);

            float xn0 = fsin_rad(30.f * (c1[0] + bs4.x)) + fsin_rev(c2[0] * 0.000244140625f);
            float xn1 = fsin_rad(30.f * (c1[1] + bs4.y)) + fsin_rev(c2[1] * 0.000244140625f);
            float xn2 = fsin_rad(30.f * (c1[2] + bs4.z)) + fsin_rev(c2[2] * 0.000244140625f);
            float xn3 = fsin_rad(30.f * (c1[3] + bs4.w)) + fsin_rev(c2[3] * 0.000244140625f);
            P[ct][0] = pk16(xn0, xn1);
            P[ct][1] = pk16(xn2, xn3);
        }

        // ---- in-register exchange: C-layout -> B-frag layout (16 bpermute + 8 select) ----
        #pragma unroll
        for (int kb = 0; kb < 2; ++kb) {
            unsigned int w[4];
            #pragma unroll
            for (int m = 0; m < 4; ++m) {
                int idx = (m < 2) ? idxA : idxB;
                int lo = __builtin_amdgcn_ds_bpermute(idx, (int)P[2 * kb + 0][m & 1]);
                int hi = __builtin_amdgcn_ds_bpermute(idx, (int)P[2 * kb + 1][m & 1]);
                w[m] = (unsigned int)(hiHalf ? hi : lo);
            }
            Xb[kb] = __builtin_bit_cast(f16x8, (u32x4){w[0], w[1], w[2], w[3]});
        }

        // ---- phase C: C = X(A) x WoutB(B); C row=point=hi4*4+r, col=feat=r15 ----
        #pragma unroll
        for (int ct = 0; ct < 8; ++ct) {
            const _Float16* bp = WoB + ((lvl * 8 + ct) * 2) * 512 + hi4 * 128 + r15 * 8;
            f16x8 B0 = *(const f16x8*)bp;
            f16x8 B1 = *(const f16x8*)(bp + 512);
            float bov = bout[lvl * 128 + ct * 16 + r15];
            f32x4 c = {0.f, 0.f, 0.f, 0.f};
            c = __builtin_amdgcn_mfma_f32_16x16x32_f16(Xb[0], B0, c, 0, 0, 0);
            c = __builtin_amdgcn_mfma_f32_16x16x32_f16(Xb[1], B1, c, 0, 0, 0);
            float s0 = fsin_rad(30.f * (c[0] + bov));
            float s1 = fsin_rad(30.f * (c[1] + bov));
            float s2 = fsin_rad(30.f * (c[2] + bov));
            float s3 = fsin_rad(30.f * (c[3] + bov));
            accP[ct][0] = accP[ct][0] + __builtin_bit_cast(f16x2, pk16(s0, s1));
            accP[ct][1] = accP[ct][1] + __builtin_bit_cast(f16x2, pk16(s2, s3));
        }
    }

    // ---- store: row=point=pbase+16wv+hi4*4+r, col=ct*16+r15 (coalesced over r15) ----
    #pragma unroll
    for (int s = 0; s < 2; ++s)
        #pragma unroll
        for (int r2 = 0; r2 < 2; ++r2) {
            int row = pbase + wv * 16 + hi4 * 4 + s * 2 + r2;
            #pragma unroll
            for (int ct = 0; ct < 8; ++ct) {
                float v = (float)accP[ct][s][r2];
                __builtin_nontemporal_store(v, &out[(size_t)row * 128 + ct * 16 + r15]);
            }
        }
}

extern "C" void kernel_launch(void* const* d_in, const int* in_sizes, int n_in,
                              void* d_out, int out_size, void* d_ws, size_t ws_size,
                              hipStream_t stream) {
    const float* in_pos = (const float*)d_in[0];
    const float* table  = (const float*)d_in[1];
    const float* ffn    = (const float*)d_in[2];
    const float* W0     = (const float*)d_in[3];
    const float* b0     = (const float*)d_in[4];
    const float* Ws     = (const float*)d_in[5];
    const float* bs     = (const float*)d_in[6];
    const float* Wout   = (const float*)d_in[7];
    const float* bout   = (const float*)d_in[8];
    float* out = (float*)d_out;
    _Float16* ws = (_Float16*)d_ws;

    // ws layout: [0, 51200) f16 weights; table f16 at 65536 (128 KB offset), 32 MB
    const size_t need = 65536u * 2u + (size_t)NLVL * TSIZE * 8u * 2u;
    const bool f16tab = (ws_size >= need);
    _Float16* tab16 = ws + 65536;

    prep_weights<<<dim3(200), dim3(256), 0, stream>>>(Ws, Wout, ffn, ws);

    const int n = in_sizes[0] / 3;    // 524288
    if (f16tab) {
        prep_table<<<dim3((NLVL * TSIZE * 8) / 256), dim3(256), 0, stream>>>(table, tab16);
        ffb_main<true><<<dim3(n / MBLK), dim3(256), 0, stream>>>(
            in_pos, table, tab16, W0, b0, bs, bout, ws, out);
    } else {
        ffb_main<false><<<dim3(n / MBLK), dim3(256), 0, stream>>>(
            in_pos, table, tab16, W0, b0, bs, bout, ws, out);
    }
}

// Round 10
// 255.151 us; speedup vs baseline: 2.1434x; 1.3171x over previous
//
#include <hip/hip_runtime.h>
#include <cstdint>
#include <cstddef>

#define NLVL 4
#define TSIZE (1u << 19)
#define NH 64
#define NOUT 128
#define MBLK 128           // points per workgroup; 8 waves x 16 points
#define PANEL 12800        // f16 elems per level panel: WsA 4096 | Ff 512 | WoB 8192

typedef _Float16 f16x8 __attribute__((ext_vector_type(8)));
typedef _Float16 f16x2 __attribute__((ext_vector_type(2)));
typedef float f32x4 __attribute__((ext_vector_type(4)));
typedef unsigned short u16x8 __attribute__((ext_vector_type(8)));
typedef unsigned int u32x4 __attribute__((ext_vector_type(4)));

__device__ __forceinline__ float fsin_rad(float x) {
    return __builtin_amdgcn_sinf(__builtin_amdgcn_fractf(x * 0.15915494309189535f));
}
__device__ __forceinline__ float fsin_rev(float r) {
    return __builtin_amdgcn_sinf(__builtin_amdgcn_fractf(r));
}
__device__ __forceinline__ unsigned short h2u(_Float16 h) {
    return __builtin_bit_cast(unsigned short, h);
}
__device__ __forceinline__ unsigned int pk16(float a, float b) {
    return __builtin_bit_cast(unsigned int, __builtin_amdgcn_cvt_pkrtz(a, b));
}
// async global->LDS, 16B per lane; lds dest = wave-uniform base + lane*16
__device__ __forceinline__ void gl_lds16(const _Float16* g, _Float16* l) {
    __builtin_amdgcn_global_load_lds(
        (const __attribute__((address_space(1))) void*)g,
        (__attribute__((address_space(3))) void*)l, 16, 0, 0);
}

// ---- prep 1: weights -> per-level packed panels in d_ws (f16) ----
// panel[lvl] (f16 offsets): [0,4096)  WsA: (c*64+k) ^ ((c&7)<<3)   (swizzled A-frags)
//                           [4096,4608) Ff: c*8+k
//                           [4608,12800) WoB: (ct*2+kb)*512 + hi4*128 + r15*8 + j
__global__ void prep_weights(const float* __restrict__ Ws,
                             const float* __restrict__ Wout,
                             const float* __restrict__ ffn,
                             _Float16* __restrict__ ws)
{
    int i = blockIdx.x * 256 + threadIdx.x;
    if (i < 16384) {                       // Ws [4][64 k][64 c]
        int l = i >> 12, r = i & 4095, k = r >> 6, c = r & 63;
        ws[l * PANEL + ((c * 64 + k) ^ ((c & 7) << 3))] = (_Float16)Ws[i];
    } else if (i < 18432) {                // ffn [4][8 k][64 c]
        int j = i - 16384;
        int l = j >> 9, r = j & 511, k = r >> 6, c = r & 63;
        ws[l * PANEL + 4096 + c * 8 + k] = (_Float16)ffn[j];
    } else if (i < 51200) {                // Wout [4][64 k][128 c]
        int j = i - 18432;
        int l = j >> 13, rem = j & 8191, k = rem >> 7, c = rem & 127;
        int ct = c >> 4, r15 = c & 15, kb = k >> 5, hi4 = (k >> 3) & 3, jj = k & 7;
        ws[l * PANEL + 4608 + (ct * 2 + kb) * 512 + hi4 * 128 + r15 * 8 + jj] =
            (_Float16)Wout[j];
    }
}

// ---- prep 2: table f32 -> f16 * 4096 ----
__global__ __launch_bounds__(256) void prep_table(const float* __restrict__ table,
                                                  _Float16* __restrict__ tab16)
{
    int i = blockIdx.x * 256 + threadIdx.x;            // 16,777,216 elems
    float v = __builtin_nontemporal_load(table + i);
    tab16[i] = (_Float16)(v * 4096.f);
}

template <bool F16TAB>
__global__ __launch_bounds__(512, 2)
void ffb_main(const float* __restrict__ in_pos,
              const float* __restrict__ table,
              const _Float16* __restrict__ tab16,
              const float* __restrict__ W0,
              const float* __restrict__ b0,
              const float* __restrict__ bs,
              const float* __restrict__ bout,
              const _Float16* __restrict__ wsg,
              float* __restrict__ out)
{
    __shared__ __align__(16) _Float16 wbuf[2][PANEL];            // 51200 B dbuf panels
    __shared__ __align__(16) unsigned short gS[NLVL][MBLK][8];   // 8192 B, g * 4096

    const int tid = threadIdx.x;
    const int pbase = blockIdx.x * MBLK;
    const int lane = tid & 63;
    const int wv = tid >> 6;
    const int r15 = lane & 15;
    const int hi4 = lane >> 4;

    // ---------- stage 1: each thread gathers one (point, level) ----------
    {
        const int p = tid & (MBLK - 1);
        const int lv = tid >> 7;
        const float px = in_pos[3 * (pbase + p) + 0];
        const float py = in_pos[3 * (pbase + p) + 1];
        const float pz = in_pos[3 * (pbase + p) + 2];
        const float qx = (px + 1.f) * 0.5f, qy = (py + 1.f) * 0.5f, qz = (pz + 1.f) * 0.5f;
        const uint32_t P1 = 2654435761u, P2 = 805459861u;

        const float res = (float)(16 << lv);
        float gx = qx * res, gy = qy * res, gz = qz * res;
        float fx0 = floorf(gx), fy0 = floorf(gy), fz0 = floorf(gz);
        float fx = gx - fx0, fy = gy - fy0, fz = gz - fz0;
        uint32_t ux = (uint32_t)fx0, uy = (uint32_t)fy0, uz = (uint32_t)fz0;
        uint32_t hx0 = ux, hx1 = ux + 1u;
        uint32_t hy0 = uy * P1, hy1 = hy0 + P1;
        uint32_t hz0 = uz * P2, hz1 = hz0 + P2;

        uint32_t hh[8];
        float    wgt[8];
        #pragma unroll
        for (int c = 0; c < 8; ++c) {
            hh[c] = (((c & 4) ? hx1 : hx0) ^ ((c & 2) ? hy1 : hy0)
                     ^ ((c & 1) ? hz1 : hz0)) & (TSIZE - 1u);
            wgt[c] = ((c & 4) ? fx : 1.f - fx) * ((c & 2) ? fy : 1.f - fy)
                   * ((c & 1) ? fz : 1.f - fz);
        }

        if (F16TAB) {
            const _Float16* tl = tab16 + (size_t)lv * TSIZE * 8;
            u16x8 vv[8];
            #pragma unroll
            for (int c = 0; c < 8; ++c)
                vv[c] = *(const u16x8*)(tl + (size_t)hh[c] * 8);
            f16x2 acc2[4];
            #pragma unroll
            for (int q = 0; q < 4; ++q) acc2[q] = (f16x2){(_Float16)0.f, (_Float16)0.f};
            #pragma unroll
            for (int c = 0; c < 8; ++c) {
                _Float16 wh = (_Float16)wgt[c];
                f16x2 ww = {wh, wh};
                const f16x2* vp = (const f16x2*)&vv[c];
                #pragma unroll
                for (int q = 0; q < 4; ++q) acc2[q] = acc2[q] + ww * vp[q];
            }
            *(u16x8*)&gS[lv][p][0] = *(u16x8*)&acc2[0];
        } else {
            const float* tl = table + (size_t)lv * TSIZE * 8;
            float g[8];
            #pragma unroll
            for (int q = 0; q < 8; ++q) g[q] = 0.f;
            #pragma unroll
            for (int c = 0; c < 8; ++c) {
                const float4* fp = (const float4*)(tl + (size_t)hh[c] * 8);
                float4 va = fp[0], vb = fp[1];
                float w = wgt[c];
                g[0] = fmaf(w, va.x, g[0]); g[1] = fmaf(w, va.y, g[1]);
                g[2] = fmaf(w, va.z, g[2]); g[3] = fmaf(w, va.w, g[3]);
                g[4] = fmaf(w, vb.x, g[4]); g[5] = fmaf(w, vb.y, g[5]);
                g[6] = fmaf(w, vb.z, g[6]); g[7] = fmaf(w, vb.w, g[7]);
            }
            u16x8 gv;
            #pragma unroll
            for (int q = 0; q < 8; ++q)
                gv[q] = h2u((_Float16)(g[q] * 4096.f));
            *(u16x8*)&gS[lv][p][0] = gv;
        }
    }

    // stage weight panel for level 0 (async; completes by the barrier)
    auto stage = [&](int l) {
        const _Float16* src = wsg + l * PANEL;
        _Float16* dst = &wbuf[l & 1][0];
        #pragma unroll
        for (int i = 0; i < 3; ++i)
            gl_lds16(src + (i * 512 + tid) * 8, dst + (i * 512 + (tid & ~63)) * 8);
        if (tid < 64)
            gl_lds16(src + (1536 + tid) * 8, dst + 1536 * 8);
    };
    stage(0);

    // ---------- layer0 directly into B-frags (no LDS roundtrip) ----------
    // Xb[kb][j] = X0[point wv*16+r15][kb*32 + hi4*8 + j]
    f16x8 Xb[2];
    {
        const int pp = pbase + wv * 16 + r15;
        const float lpx = in_pos[3 * pp + 0];
        const float lpy = in_pos[3 * pp + 1];
        const float lpz = in_pos[3 * pp + 2];
        #pragma unroll
        for (int kb = 0; kb < 2; ++kb) {
            f16x8 v;
            #pragma unroll
            for (int j = 0; j < 8; ++j) {
                const int f = kb * 32 + hi4 * 8 + j;
                float a = b0[f] + lpx * W0[f] + lpy * W0[64 + f] + lpz * W0[128 + f];
                v[j] = (_Float16)fsin_rad(30.f * a);
            }
            Xb[kb] = v;
        }
    }
    __syncthreads();   // gS visible + panel 0 staged (barrier drains vmcnt)

    // bpermute indices (byte addressing)
    const int idxA = ((lane & 16) << 3) + r15 * 4;   // src = 32*(h&1) + r15
    const int idxB = idxA + 64;                      // src += 16
    const bool hiHalf = (lane & 32) != 0;

    f16x2 accP[8][2];
    #pragma unroll
    for (int ct = 0; ct < 8; ++ct)
        #pragma unroll
        for (int s = 0; s < 2; ++s) accP[ct][s] = (f16x2){(_Float16)0.f, (_Float16)0.f};

    #pragma unroll 1
    for (int lvl = 0; lvl < NLVL; ++lvl) {
        if (lvl < NLVL - 1) stage(lvl + 1);         // prefetch next panel (other buffer)
        const _Float16* wp = &wbuf[lvl & 1][0];

        // g as B-frag: only lanes 0-15 nonzero
        f16x8 gB;
        {
            f16x8 z;
            #pragma unroll
            for (int q = 0; q < 8; ++q) z[q] = (_Float16)0.f;
            if (lane < 16)
                z = *(const f16x8*)&gS[lvl][wv * 16 + lane][0];
            gB = z;
        }

        // ---- phase B: C1 = Ws^T(A) x X(B); C col=point=lane&15, row=feat ----
        unsigned int P[4][2];
        #pragma unroll
        for (int ct = 0; ct < 4; ++ct) {
            const int i0 = ((ct * 16 + r15) * 64 + hi4 * 8) ^ ((r15 & 7) << 3);
            f16x8 A0 = *(const f16x8*)&wp[i0];
            f16x8 A1 = *(const f16x8*)&wp[i0 ^ 32];
            f16x8 Af;
            #pragma unroll
            for (int q = 0; q < 8; ++q) Af[q] = (_Float16)0.f;
            if (lane < 16)
                Af = *(const f16x8*)&wp[4096 + (ct * 16 + lane) * 8];
            float4 bs4 = *(const float4*)&bs[lvl * 64 + ct * 16 + hi4 * 4];

            f32x4 c1 = {0.f, 0.f, 0.f, 0.f};
            c1 = __builtin_amdgcn_mfma_f32_16x16x32_f16(A0, Xb[0], c1, 0, 0, 0);
            c1 = __builtin_amdgcn_mfma_f32_16x16x32_f16(A1, Xb[1], c1, 0, 0, 0);
            f32x4 c2 = {0.f, 0.f, 0.f, 0.f};
            c2 = __builtin_amdgcn_mfma_f32_16x16x32_f16(Af, gB, c2, 0, 0, 0);

            float xn0 = fsin_rad(30.f * (c1[0] + bs4.x)) + fsin_rev(c2[0] * 0.000244140625f);
            float xn1 = fsin_rad(30.f * (c1[1] + bs4.y)) + fsin_rev(c2[1] * 0.000244140625f);
            float xn2 = fsin_rad(30.f * (c1[2] + bs4.z)) + fsin_rev(c2[2] * 0.000244140625f);
            float xn3 = fsin_rad(30.f * (c1[3] + bs4.w)) + fsin_rev(c2[3] * 0.000244140625f);
            P[ct][0] = pk16(xn0, xn1);
            P[ct][1] = pk16(xn2, xn3);
        }

        // ---- in-register exchange: C-layout -> B-frag layout ----
        #pragma unroll
        for (int kb = 0; kb < 2; ++kb) {
            unsigned int w[4];
            #pragma unroll
            for (int m = 0; m < 4; ++m) {
                int idx = (m < 2) ? idxA : idxB;
                int lo = __builtin_amdgcn_ds_bpermute(idx, (int)P[2 * kb + 0][m & 1]);
                int hi = __builtin_amdgcn_ds_bpermute(idx, (int)P[2 * kb + 1][m & 1]);
                w[m] = (unsigned int)(hiHalf ? hi : lo);
            }
            Xb[kb] = __builtin_bit_cast(f16x8, (u32x4){w[0], w[1], w[2], w[3]});
        }

        // ---- phase C: C = X(A) x WoutB(B); row=point, col=feat ----
        #pragma unroll
        for (int ct = 0; ct < 8; ++ct) {
            const _Float16* bp = &wp[4608 + (ct * 2) * 512 + hi4 * 128 + r15 * 8];
            f16x8 B0 = *(const f16x8*)bp;
            f16x8 B1 = *(const f16x8*)(bp + 512);
            float bov = bout[lvl * 128 + ct * 16 + r15];
            f32x4 c = {0.f, 0.f, 0.f, 0.f};
            c = __builtin_amdgcn_mfma_f32_16x16x32_f16(Xb[0], B0, c, 0, 0, 0);
            c = __builtin_amdgcn_mfma_f32_16x16x32_f16(Xb[1], B1, c, 0, 0, 0);
            float s0 = fsin_rad(30.f * (c[0] + bov));
            float s1 = fsin_rad(30.f * (c[1] + bov));
            float s2 = fsin_rad(30.f * (c[2] + bov));
            float s3 = fsin_rad(30.f * (c[3] + bov));
            accP[ct][0] = accP[ct][0] + __builtin_bit_cast(f16x2, pk16(s0, s1));
            accP[ct][1] = accP[ct][1] + __builtin_bit_cast(f16x2, pk16(s2, s3));
        }

        if (lvl < NLVL - 1) __syncthreads();   // all read wp; next panel staged
    }

    // ---- store: row=point=pbase+16wv+hi4*4+r, col=ct*16+r15 (coalesced) ----
    #pragma unroll
    for (int s = 0; s < 2; ++s)
        #pragma unroll
        for (int r2 = 0; r2 < 2; ++r2) {
            int row = pbase + wv * 16 + hi4 * 4 + s * 2 + r2;
            #pragma unroll
            for (int ct = 0; ct < 8; ++ct) {
                float v = (float)accP[ct][s][r2];
                __builtin_nontemporal_store(v, &out[(size_t)row * 128 + ct * 16 + r15]);
            }
        }
}

extern "C" void kernel_launch(void* const* d_in, const int* in_sizes, int n_in,
                              void* d_out, int out_size, void* d_ws, size_t ws_size,
                              hipStream_t stream) {
    const float* in_pos = (const float*)d_in[0];
    const float* table  = (const float*)d_in[1];
    const float* ffn    = (const float*)d_in[2];
    const float* W0     = (const float*)d_in[3];
    const float* b0     = (const float*)d_in[4];
    const float* Ws     = (const float*)d_in[5];
    const float* bs     = (const float*)d_in[6];
    const float* Wout   = (const float*)d_in[7];
    const float* bout   = (const float*)d_in[8];
    float* out = (float*)d_out;
    _Float16* ws = (_Float16*)d_ws;

    // ws layout: [0, 51200) f16 weight panels; table f16 at 65536, 32 MB
    const size_t need = 65536u * 2u + (size_t)NLVL * TSIZE * 8u * 2u;
    const bool f16tab = (ws_size >= need);
    _Float16* tab16 = ws + 65536;

    prep_weights<<<dim3(200), dim3(256), 0, stream>>>(Ws, Wout, ffn, ws);

    const int n = in_sizes[0] / 3;    // 524288
    if (f16tab) {
        prep_table<<<dim3((NLVL * TSIZE * 8) / 256), dim3(256), 0, stream>>>(table, tab16);
        ffb_main<true><<<dim3(n / MBLK), dim3(512), 0, stream>>>(
            in_pos, table, tab16, W0, b0, bs, bout, ws, out);
    } else {
        ffb_main<false><<<dim3(n / MBLK), dim3(512), 0, stream>>>(
            in_pos, table, tab16, W0, b0, bs, bout, ws, out);
    }
}